// Round 1
// baseline (138.727 us; speedup 1.0000x reference)
//
#include <hip/hip_runtime.h>

#define NGRAPHS 256
#define CHUNK   2048      // edges per scatter block (E=1.6M -> 782 blocks, ~3/CU)
#define CAPG    12288     // bucket capacity per graph (mean ~6250, max ~7500 -> slack)
#define NMAX    2048      // max nodes per graph (actual ~470)

// ---- k1: node dots (32 rows/block, 16 lanes/row, float4/lane) + graph
//      boundaries + cursor zero (block 0). ----
__global__ __launch_bounds__(512) void k1_dot(
    const float* __restrict__ x,
    const int*   __restrict__ batch,
    const float* __restrict__ w_rel,
    const float* __restrict__ w_root,
    float* __restrict__ p, float* __restrict__ r,
    int* __restrict__ starts, int* __restrict__ ends,
    int* __restrict__ cursor, int N)
{
    int tid = threadIdx.x;
    if (blockIdx.x == 0 && tid < NGRAPHS) cursor[tid] = 0;
    int row = (int)blockIdx.x * 32 + (tid >> 4);
    int fq  = tid & 15;
    if (row >= N) return;
    if (fq == 0) {                       // graph boundaries (handles empty graphs)
        int b = batch[row];
        if (row == 0) {
            for (int g = 0; g < b; ++g) { starts[g] = 0; ends[g] = 0; }
            starts[b] = 0;
        } else {
            int bp = batch[row - 1];
            if (bp != b) {
                ends[bp] = row;
                for (int g = bp + 1; g < b; ++g) { starts[g] = row; ends[g] = row; }
                starts[b] = row;
            }
        }
        if (row == N - 1) {
            ends[b] = N;
            for (int g = b + 1; g < NGRAPHS; ++g) { starts[g] = N; ends[g] = N; }
        }
    }
    float4 v  = *(const float4*)(x + (size_t)row * 64 + fq * 4);
    float4 wr = ((const float4*)w_rel)[fq];
    float4 wo = ((const float4*)w_root)[fq];
    float a = v.x * wr.x + v.y * wr.y + v.z * wr.z + v.w * wr.w;
    float c = v.x * wo.x + v.y * wo.y + v.z * wo.z + v.w * wo.w;
    a += __shfl_down(a, 8); c += __shfl_down(c, 8);
    a += __shfl_down(a, 4); c += __shfl_down(c, 4);
    a += __shfl_down(a, 2); c += __shfl_down(c, 2);
    a += __shfl_down(a, 1); c += __shfl_down(c, 1);
    if (fq == 0) { p[row] = a; r[row] = c; }
}

// ---- kSc: single pass over ei. Stage packed (src<<11 | local) in LDS,
//      LDS histogram by graph, ONE global atomicAdd per (block,graph) to
//      reserve a bucket range (replaces count kernel + column-scan kernel),
//      then scatter from LDS staging. Bucket order within a graph is
//      irrelevant (kPool only sums). ----
__global__ __launch_bounds__(512) void kSc_scatter(
    const int* __restrict__ ei,          // [2,E]: src then dst
    const int* __restrict__ batch,
    const int* __restrict__ starts,
    int* __restrict__ cursor,
    unsigned* __restrict__ bucket,
    int E, int vecE)
{
    __shared__ __align__(16) unsigned stage[CHUNK];   // packed entries
    __shared__ unsigned char sbin[CHUNK];             // graph id per entry
    __shared__ int hist[NGRAPHS];
    __shared__ int wb[NGRAPHS];                       // running write cursor
    __shared__ int sst[NGRAPHS];                      // starts[] cache

    int tid = threadIdx.x;
    if (tid < NGRAPHS) { hist[tid] = 0; sst[tid] = starts[tid]; }
    __syncthreads();

    int beg = (int)blockIdx.x * CHUNK;
    int end = min(beg + CHUNK, E);
    if (vecE) {
        const int4* s4 = (const int4*)ei;
        const int4* d4 = (const int4*)(ei + E);
        for (int i = (beg >> 2) + tid; i < (end >> 2); i += 512) {
            int4 s = s4[i];
            int4 d = d4[i];
            int o = (i << 2) - beg;
            int g0 = batch[d.x], g1 = batch[d.y], g2 = batch[d.z], g3 = batch[d.w];
            int l0 = min(d.x - sst[g0], NMAX - 1);
            int l1 = min(d.y - sst[g1], NMAX - 1);
            int l2 = min(d.z - sst[g2], NMAX - 1);
            int l3 = min(d.w - sst[g3], NMAX - 1);
            uint4 st; uchar4 sb;
            st.x = ((unsigned)s.x << 11) | (unsigned)l0; sb.x = (unsigned char)g0;
            st.y = ((unsigned)s.y << 11) | (unsigned)l1; sb.y = (unsigned char)g1;
            st.z = ((unsigned)s.z << 11) | (unsigned)l2; sb.z = (unsigned char)g2;
            st.w = ((unsigned)s.w << 11) | (unsigned)l3; sb.w = (unsigned char)g3;
            *(uint4*)&stage[o] = st;                  // ds_write_b128, o%4==0
            *(uchar4*)&sbin[o] = sb;
            atomicAdd(&hist[g0], 1);
            atomicAdd(&hist[g1], 1);
            atomicAdd(&hist[g2], 1);
            atomicAdd(&hist[g3], 1);
        }
    } else {
        for (int i = beg + tid; i < end; i += 512) {
            int s = ei[i];
            int d = ei[E + i];
            int g = batch[d];
            int l = min(d - sst[g], NMAX - 1);
            int o = i - beg;
            stage[o] = ((unsigned)s << 11) | (unsigned)l;
            sbin[o]  = (unsigned char)g;
            atomicAdd(&hist[g], 1);
        }
    }
    __syncthreads();
    if (tid < NGRAPHS) {
        int h = hist[tid];
        wb[tid] = (h > 0) ? tid * CAPG + atomicAdd(&cursor[tid], h) : 0;
    }
    __syncthreads();
    int cnt = end - beg;
    for (int o = tid; o < cnt; o += 512) {
        int b = sbin[o];
        int pos = atomicAdd(&wb[b], 1);
        if (pos < (b + 1) * CAPG) bucket[pos] = stage[o];
    }
}

// ---- fallback (ws too small / N too big for packing): global atomics ----
__global__ __launch_bounds__(256) void kZ_zero(float* __restrict__ a, int N)
{
    int i = blockIdx.x * 256 + threadIdx.x;
    if (i < N) a[i] = 0.0f;
}
__global__ __launch_bounds__(256) void k2_scatter(
    const int* __restrict__ ei, const float* __restrict__ p,
    float* aggdot, int E)
{
    int i = blockIdx.x * 256 + threadIdx.x;
    if (i < E) unsafeAtomicAdd(&aggdot[ei[E + i]], p[ei[i]]);
}
__global__ __launch_bounds__(256) void kS_score(
    const float* __restrict__ aggdot, const float* __restrict__ r,
    const float* __restrict__ brel, float* __restrict__ score, int N)
{
    int i = blockIdx.x * 256 + threadIdx.x;
    if (i < N) score[i] = tanhf(aggdot[i] + brel[0] + r[i]);
}

// ---- kPool: one block per graph. Fuses the old kB (bucket accumulate +
//      tanh score, now per-graph in LDS — no global score round-trip) with
//      the stable top-k rank + compacted weighted pool. ----
__global__ __launch_bounds__(512) void kPool(
    const float* __restrict__ x,
    const float* __restrict__ p,
    const float* __restrict__ r,
    const float* __restrict__ brel,
    const unsigned* __restrict__ bucket,
    const int* __restrict__ cursor,
    const int* __restrict__ starts,
    const int* __restrict__ ends,
    const float* __restrict__ score_g,   // non-null => fallback path
    float* __restrict__ out)
{
    __shared__ __align__(16) float sc[NMAX];
    __shared__ float acc[NMAX];
    __shared__ int   kidx[NMAX / 2 + 64];
    __shared__ float kw[NMAX / 2 + 64];
    __shared__ float accs[8][64][4];
    __shared__ int   pctr;

    int g   = blockIdx.x;
    int tid = threadIdx.x;
    int start = starts[g];
    int n     = ends[g] - start;
    if (n > NMAX) n = NMAX;              // safety clamp (never hit)
    int k = (n + 1) >> 1;                // ceil(0.5*n) == kept count
    if (tid == 0) pctr = 0;

    if (score_g) {
        for (int i = tid; i < n; i += 512) sc[i] = score_g[start + i];
    } else {
        for (int i = tid; i < n; i += 512) acc[i] = 0.0f;
        __syncthreads();
        int lo  = g * CAPG;
        int cnt = min(cursor[g], CAPG);
        const uint4* bk4 = (const uint4*)(bucket + lo);   // CAPG%4==0 -> aligned
        int quart = cnt >> 2;
        for (int e = tid; e < quart; e += 512) {
            uint4 u = bk4[e];
            float v0 = p[u.x >> 11], v1 = p[u.y >> 11];
            float v2 = p[u.z >> 11], v3 = p[u.w >> 11];
            atomicAdd(&acc[u.x & 2047u], v0);             // ds_add_f32
            atomicAdd(&acc[u.y & 2047u], v1);
            atomicAdd(&acc[u.z & 2047u], v2);
            atomicAdd(&acc[u.w & 2047u], v3);
        }
        int tail = cnt & 3;
        if (tid < tail) {
            unsigned u = bucket[lo + (quart << 2) + tid];
            atomicAdd(&acc[u & 2047u], p[u >> 11]);
        }
        __syncthreads();
        float bb = brel[0];
        for (int i = tid; i < n; i += 512)
            sc[i] = tanhf(acc[i] + bb + r[start + i]);
    }
    __syncthreads();

    // stable rank (score desc, index asc) + compaction; j-loop float4 LDS
    int n4 = n & ~3;
    for (int i = tid; i < n; i += 512) {
        float si = sc[i];
        int rank = 0;
        int j = 0;
        for (; j < n4; j += 4) {
            float4 s4 = *(const float4*)&sc[j];
            rank += (s4.x > si) || (s4.x == si && (j + 0) < i);
            rank += (s4.y > si) || (s4.y == si && (j + 1) < i);
            rank += (s4.z > si) || (s4.z == si && (j + 2) < i);
            rank += (s4.w > si) || (s4.w == si && (j + 3) < i);
        }
        for (; j < n; ++j) {
            float sj = sc[j];
            rank += (sj > si) || (sj == si && j < i);
        }
        if (rank < k) {
            int pos = atomicAdd(&pctr, 1);
            kidx[pos] = i;
            kw[pos]   = si;
        }
    }
    __syncthreads();
    int k32 = (k + 31) & ~31;
    for (int e = k + tid; e < k32; e += 512) { kidx[e] = 0; kw[e] = 0.0f; }
    __syncthreads();

    // weighted pool over compacted kept list
    int wg   = tid >> 6;
    int lane = tid & 63;
    int rgrp = lane >> 4;
    int fq   = lane & 15;
    float a0 = 0.0f, a1 = 0.0f, a2 = 0.0f, a3 = 0.0f;
    #pragma unroll 2
    for (int e = wg * 4 + rgrp; e < k32; e += 32) {
        float wv = kw[e];
        int row  = start + kidx[e];
        const float4 v = *(const float4*)(x + (size_t)row * 64 + fq * 4);
        a0 += v.x * wv; a1 += v.y * wv; a2 += v.z * wv; a3 += v.w * wv;
    }
    accs[wg][lane][0] = a0; accs[wg][lane][1] = a1;
    accs[wg][lane][2] = a2; accs[wg][lane][3] = a3;
    __syncthreads();
    if (tid < 64) {
        float sum = 0.0f;
        #pragma unroll
        for (int gg = 0; gg < 8; ++gg)
            #pragma unroll
            for (int rg = 0; rg < 4; ++rg)
                sum += accs[gg][rg * 16 + (tid >> 2)][tid & 3];
        out[(size_t)g * 64 + tid] = sum / fmaxf((float)k, 1.0f);
    }
}

extern "C" void kernel_launch(void* const* d_in, const int* in_sizes, int n_in,
                              void* d_out, int out_size, void* d_ws, size_t ws_size,
                              hipStream_t stream) {
    const float* x      = (const float*)d_in[0];
    const int*   ei     = (const int*)  d_in[1];
    const int*   batch  = (const int*)  d_in[2];
    const float* w_rel  = (const float*)d_in[3];
    const float* b_rel  = (const float*)d_in[4];
    const float* w_root = (const float*)d_in[5];
    float* out = (float*)d_out;

    int N = in_sizes[2];
    int E = in_sizes[1] / 2;
    int NBLKE = (E + CHUNK - 1) / CHUNK;
    int vecE  = ((E & 3) == 0);
    int dotblks = (N + 31) / 32;

    // ws layout (4B units): p[N], r[N], starts[256], ends[256], cursor[256],
    // (align16) bucket u32[NGRAPHS*CAPG]; fallback aliases score/aggdot after cursor
    float* p      = (float*)d_ws;
    float* r      = p + (size_t)N;
    int*   starts = (int*)(r + (size_t)N);
    int*   ends   = starts + NGRAPHS;
    int*   cursor = ends + NGRAPHS;
    size_t boff = (size_t)2 * N + 3 * NGRAPHS;
    boff = (boff + 3) & ~(size_t)3;                  // 16B-align bucket
    unsigned* bucket = (unsigned*)d_ws + boff;
    size_t need = (boff + (size_t)NGRAPHS * CAPG) * 4;

    bool binned = (need <= ws_size) && (N < (1 << 17));   // src fits 17 bits

    k1_dot<<<dotblks, 512, 0, stream>>>(x, batch, w_rel, w_root,
                                        p, r, starts, ends, cursor, N);
    if (binned) {
        kSc_scatter<<<NBLKE, 512, 0, stream>>>(ei, batch, starts, cursor,
                                               bucket, E, vecE);
        kPool<<<NGRAPHS, 512, 0, stream>>>(x, p, r, b_rel, bucket, cursor,
                                           starts, ends, nullptr, out);
    } else {
        float* score  = (float*)(cursor + NGRAPHS);
        float* aggdot = score + (size_t)N;
        kZ_zero<<<(N + 255) / 256, 256, 0, stream>>>(aggdot, N);
        k2_scatter<<<(E + 255) / 256, 256, 0, stream>>>(ei, p, aggdot, E);
        kS_score<<<(N + 255) / 256, 256, 0, stream>>>(aggdot, r, b_rel, score, N);
        kPool<<<NGRAPHS, 512, 0, stream>>>(x, p, r, b_rel, nullptr, nullptr,
                                           starts, ends, score, out);
    }
}